// Round 6
// baseline (940.118 us; speedup 1.0000x reference)
//
#include <hip/hip_runtime.h>
#include <math.h>

#define BATCH 4
#define HH 512
#define WW 1024
#define NPIX (HH*WW)          // 524288 = 2^19
#define CCAP 196608           // compaction capacity per image (expected ~161.7k valid)
#define GX 64
#define GY 48
#define NCELL (GX*GY)         // 3072 cells, 0.0625 x 0.0625 over [-1,3]x[-1,2]
#define CELL 0.0625f
#define INVCELL 16.0f
#define SEGSZ 512             // pixels per argmax-cache segment
#define NSEGMAX (CCAP/SEGSZ)  // 384
#define DLCAP 2048            // dirty-segment list capacity
#define CKCAP 1600            // combined 256-px chunk queue (worst/seed 792, x2)
#define CKBCAP 512            // combined chunks with cached ballots

// ---------------- XLA:CPU f32 math replicas (unchanged from passing rounds) ----
__device__ __forceinline__ float xla_tanhf(float x) {
  if (fabsf(x) < 0.0004f) return x;
  float xc = fminf(fmaxf(x, -7.90531110763549805f), 7.90531110763549805f);
  float x2 = __fmul_rn(xc, xc);
  float p = -2.76076847742355e-16f;
  p = fmaf(x2, p, 2.00018790482477e-13f);
  p = fmaf(x2, p, -8.60467152213735e-11f);
  p = fmaf(x2, p, 5.12229709037114e-08f);
  p = fmaf(x2, p, 1.48572235717979e-05f);
  p = fmaf(x2, p, 6.37261928875436e-04f);
  p = fmaf(x2, p, 4.89352455891786e-03f);
  p = __fmul_rn(xc, p);
  float q = fmaf(x2, 1.19825839466702e-06f, 1.18534705686654e-04f);
  q = fmaf(x2, q, 2.26843463243900e-03f);
  q = fmaf(x2, q, 4.89352518554385e-03f);
  return __fdiv_rn(p, q);
}

__device__ __forceinline__ float xla_expf(float x) {
  float xc = fminf(fmaxf(x, -87.3365478515625f), 88.72283935546875f);
  float m = floorf(fmaf(xc, 1.44269504088896341f, 0.5f));
  float r = fmaf(m, -0.693359375f, xc);
  r = fmaf(m, 2.12194440e-4f, r);
  float r2 = __fmul_rn(r, r);
  float p = 1.9875691500e-4f;
  p = fmaf(p, r, 1.3981999507e-3f);
  p = fmaf(p, r, 8.3334519073e-3f);
  p = fmaf(p, r, 4.1665795894e-2f);
  p = fmaf(p, r, 1.6666665459e-1f);
  p = fmaf(p, r, 5.0000001201e-1f);
  float y = fmaf(r2, p, r);
  y = __fadd_rn(y, 1.0f);
  return ldexpf(y, (int)m);
}

__device__ __forceinline__ float xla_sigmoidf(float x) {
  return fmaf(0.5f, xla_tanhf(__fmul_rn(0.5f, x)), 0.5f);
}

// Proposal test — byte-identical decision logic to the passing kernels.
__device__ __forceinline__ bool prop_test(float2 e, float cx, float cy,
                                          float den0, float den1,
                                          float inv0, float inv1) {
  float d0 = __fsub_rn(e.x, cx), d1 = __fsub_rn(e.y, cy);
  float dd0 = __fmul_rn(d0, d0), dd1 = __fmul_rn(d1, d1);
  float zf = fmaf(dd0, inv0, __fmul_rn(dd1, inv1));
  if (zf < 0.6921472f) return true;
  if (zf <= 0.6941472f) {
    float t0 = __fdiv_rn(dd0, den0);
    float t1 = __fdiv_rn(dd1, den1);
    float z = __fadd_rn(t0, t1);
    return xla_expf(-z) > 0.5f;
  }
  return false;
}

__device__ __forceinline__ int cell_of_x(float ex) {
  int c = (int)((ex + 1.0f) * INVCELL);
  return min(max(c, 0), GX - 1);
}
__device__ __forceinline__ int cell_of_y(float ey) {
  int c = (int)((ey + 1.0f) * INVCELL);
  return min(max(c, 0), GY - 1);
}

// bits [a,b) of a 64-bit mask; requires 0 <= a < 64, 0 <= b <= 64, a <= b.
__device__ __forceinline__ unsigned long long maskrange64(int a, int b) {
  unsigned long long mb = (b >= 64) ? ~0ULL : ((1ULL << b) - 1ULL);
  unsigned long long ma = (1ULL << a) - 1ULL;
  return mb & ~ma;
}

// ---------------- DPP wave64 primitives ----------------------------------------
__device__ __forceinline__ int wave_sum_bcast_i32(int x) {
  x += __builtin_amdgcn_update_dpp(0, x, 0x111, 0xf, 0xf, false);
  x += __builtin_amdgcn_update_dpp(0, x, 0x112, 0xf, 0xf, false);
  x += __builtin_amdgcn_update_dpp(0, x, 0x114, 0xf, 0xf, false);
  x += __builtin_amdgcn_update_dpp(0, x, 0x118, 0xf, 0xf, false);
  x += __builtin_amdgcn_update_dpp(0, x, 0x142, 0xa, 0xf, false);
  x += __builtin_amdgcn_update_dpp(0, x, 0x143, 0xc, 0xf, false);
  return __builtin_amdgcn_readlane(x, 63);
}

__device__ __forceinline__ int wave_scan_incl_i32(int x) {   // per-lane inclusive
  x += __builtin_amdgcn_update_dpp(0, x, 0x111, 0xf, 0xf, false);
  x += __builtin_amdgcn_update_dpp(0, x, 0x112, 0xf, 0xf, false);
  x += __builtin_amdgcn_update_dpp(0, x, 0x114, 0xf, 0xf, false);
  x += __builtin_amdgcn_update_dpp(0, x, 0x118, 0xf, 0xf, false);
  x += __builtin_amdgcn_update_dpp(0, x, 0x142, 0xa, 0xf, false);
  x += __builtin_amdgcn_update_dpp(0, x, 0x143, 0xc, 0xf, false);
  return x;
}

// Branch-free 64-bit (hi,lo) max across 64 lanes; broadcasts to all lanes.
// Keys are (score_bits, ~pix) — unique, nonzero-hi when live.
__device__ __forceinline__ void wave_max_key64(unsigned &h, unsigned &l) {
#define KSTEP(ctrl, rm)                                                        \
  { unsigned nh = (unsigned)__builtin_amdgcn_update_dpp(0, (int)h, ctrl, rm, 0xf, false); \
    unsigned nl = (unsigned)__builtin_amdgcn_update_dpp(0, (int)l, ctrl, rm, 0xf, false); \
    if (nh > h || (nh == h && nl > l)) { h = nh; l = nl; } }
  KSTEP(0x111, 0xf) KSTEP(0x112, 0xf) KSTEP(0x114, 0xf) KSTEP(0x118, 0xf)
  KSTEP(0x142, 0xa) KSTEP(0x143, 0xc)
#undef KSTEP
  h = (unsigned)__builtin_amdgcn_readlane((int)h, 63);
  l = (unsigned)__builtin_amdgcn_readlane((int)l, 63);
}

// ---------------- kernels ----------------

__global__ __launch_bounds__(1024) void fill_kernel(int* out, int val, int n) {
  int i = blockIdx.x * 1024 + threadIdx.x;
  if (i < n) out[i] = val;
}

// pass A: zero output, LDS-aggregated histogram (one global atomic per block+cell)
__global__ __launch_bounds__(1024) void hist_kernel(const float* __restrict__ in,
                                                    int* __restrict__ out,
                                                    int* __restrict__ hist) {
  __shared__ int lh[NCELL];
  int tid = threadIdx.x;
  int gid = blockIdx.x * 1024 + tid;
  int b = gid >> 19;
  int p = gid & (NPIX - 1);
  for (int j = tid; j < NCELL; j += 1024) lh[j] = 0;
  __syncthreads();
  const float* base = in + (size_t)b * 5 * NPIX;
  float seed = base[(size_t)4 * NPIX + p];
  out[gid] = 0;
  if (seed > 0.5f) {
    float ox = base[p];
    float oy = base[(size_t)NPIX + p];
    int col = p & (WW - 1);
    int row = p >> 10;
    float gx = __fmul_rn((float)col, 2.0f / 1023.0f);
    float gy = __fmul_rn((float)row, 1.0f / 511.0f);
    float ex = __fadd_rn(xla_tanhf(ox), gx);
    float ey = __fadd_rn(xla_tanhf(oy), gy);
    atomicAdd(&lh[cell_of_y(ey) * GX + cell_of_x(ex)], 1);
  }
  __syncthreads();
  for (int j = tid; j < NCELL; j += 1024) {
    int c = lh[j];
    if (c) atomicAdd(&hist[b * NCELL + j], c);
  }
}

// pass B: exclusive scan of the cell counts per image (one block per image)
__global__ __launch_bounds__(1024) void scan_kernel(const int* __restrict__ hist,
                                                    int* __restrict__ off,
                                                    int* __restrict__ cursor) {
  __shared__ int s_c[NCELL];
  __shared__ int s_ps[1024];
  int b = blockIdx.x, t = threadIdx.x;
  const int* h = hist + b * NCELL;
  for (int i = t; i < NCELL; i += 1024) s_c[i] = h[i];
  __syncthreads();
  int a = s_c[3 * t], b2 = s_c[3 * t + 1], c2 = s_c[3 * t + 2];
  int th = a + b2 + c2;
  s_ps[t] = th;
  __syncthreads();
  for (int d = 1; d < 1024; d <<= 1) {
    int v = (t >= d) ? s_ps[t - d] : 0;
    __syncthreads();
    s_ps[t] += v;
    __syncthreads();
  }
  int excl = s_ps[t] - th;
  int* ob = off + b * (NCELL + 1);
  int* cb = cursor + b * NCELL;
  ob[3 * t] = excl;              cb[3 * t] = excl;
  ob[3 * t + 1] = excl + a;      cb[3 * t + 1] = excl + a;
  ob[3 * t + 2] = excl + a + b2; cb[3 * t + 2] = excl + a + b2;
  if (t == 1023) ob[NCELL] = s_ps[1023];
}

// pass C: LDS-aggregated scatter (within-cell order arbitrary; downstream is
// order-independent, tiebreak uses global pixel index)
__global__ __launch_bounds__(1024) void scatter_kernel(const float* __restrict__ in,
                                                       int* __restrict__ cursor,
                                                       float2* __restrict__ emb,
                                                       int2* __restrict__ pk) {
  __shared__ int lh[NCELL];
  __shared__ int lbase[NCELL];
  int tid = threadIdx.x;
  int gid = blockIdx.x * 1024 + tid;
  int b = gid >> 19;
  int p = gid & (NPIX - 1);
  for (int j = tid; j < NCELL; j += 1024) lh[j] = 0;
  __syncthreads();
  const float* base = in + (size_t)b * 5 * NPIX;
  float seed = base[(size_t)4 * NPIX + p];
  bool valid = seed > 0.5f;
  float ex = 0.0f, ey = 0.0f, smv = 0.0f;
  int cell = 0, sl = 0;
  if (valid) {
    float ox = base[p];
    float oy = base[(size_t)NPIX + p];
    int col = p & (WW - 1);
    int row = p >> 10;
    float gx = __fmul_rn((float)col, 2.0f / 1023.0f);
    float gy = __fmul_rn((float)row, 1.0f / 511.0f);
    ex = __fadd_rn(xla_tanhf(ox), gx);
    ey = __fadd_rn(xla_tanhf(oy), gy);
    smv = xla_sigmoidf(seed);
    cell = cell_of_y(ey) * GX + cell_of_x(ex);
    sl = atomicAdd(&lh[cell], 1);
  }
  __syncthreads();
  for (int j = tid; j < NCELL; j += 1024) {
    int c = lh[j];
    if (c) lbase[j] = atomicAdd(&cursor[b * NCELL + j], c);
  }
  __syncthreads();
  if (valid) {
    int slot = lbase[cell] + sl;
    if (slot < CCAP) {
      emb[(size_t)b * CCAP + slot] = make_float2(ex, ey);
      pk[(size_t)b * CCAP + slot]  = make_int2(__float_as_int(smv), p);
    }
  }
}

// Segment scan (SEGSZ=512: 8 strips of 64). EXACT per-segment top-2 keys with
// indices ci1/ci2; dirty-rescan triggers on removal of EITHER, so between
// rescans the stored top-2 is always exact (other removals can't change it).
// Winner lane precomputes reciprocals + outer radii (rx,ry) in aux2.
__device__ __forceinline__ void seg_rescan(int s, int V, int lane,
    const unsigned* s_uncl, const int2* __restrict__ pk,
    const float2* __restrict__ emb, const float* __restrict__ base,
    unsigned long long* s_segkey, unsigned long long* s_segkey2,
    int* s_segci, int* s_segci2, float4* s_segaux, float4* s_segaux2,
    bool checkAlive) {
  unsigned k1h = 0, k1l = 0, k2h = 0, k2l = 0; int c1 = -1, c2 = -1, bpx = 0;
  #pragma unroll
  for (int j = 0; j < 8; ++j) {
    int i = (s << 9) + (j << 6) + lane;
    if (i < V) {
      bool alive = !checkAlive || ((s_uncl[i >> 5] >> (i & 31)) & 1u);
      if (alive) {
        int2 v = pk[i];
        unsigned vh = (unsigned)v.x, vl = (unsigned)(~v.y);
        if (vh > k1h || (vh == k1h && vl > k1l)) {
          k2h = k1h; k2l = k1l; c2 = c1; k1h = vh; k1l = vl; c1 = i; bpx = v.y;
        } else if (vh > k2h || (vh == k2h && vl > k2l)) {
          k2h = vh; k2l = vl; c2 = i;
        }
      }
    }
  }
  unsigned m1h = k1h, m1l = k1l;
  wave_max_key64(m1h, m1l);
  if (m1h == 0u) {                      // segment fully dead
    if (lane == 0) {
      s_segkey[s] = 0ULL; s_segkey2[s] = 0ULL;
      s_segci[s] = -1; s_segci2[s] = -1;
    }
    return;
  }
  bool own1 = (k1h == m1h && k1l == m1l);         // keys unique -> one lane
  unsigned ch = own1 ? k2h : k1h, cl = own1 ? k2l : k1l;
  int cc = own1 ? c2 : c1;
  unsigned m2h = ch, m2l = cl;
  wave_max_key64(m2h, m2l);
  if (m2h == 0u && m2l == 0u) {
    if (lane == 0) { s_segkey2[s] = 0ULL; s_segci2[s] = -1; }
  } else if (ch == m2h && cl == m2l) {            // unique candidate owner
    s_segkey2[s] = ((unsigned long long)m2h << 32) | m2l;
    s_segci2[s] = cc;
  }
  if (own1) {
    s_segkey[s] = ((unsigned long long)m1h << 32) | m1l;
    s_segci[s] = c1;
    float2 e = emb[c1];
    float sxv = base[(size_t)2 * NPIX + bpx];
    float syv = base[(size_t)3 * NPIX + bpx];
    float d0 = __fmul_rn(2.0f, __fmul_rn(sxv, sxv));   // ref: 2.0 * s**2
    float d1 = __fmul_rn(2.0f, __fmul_rn(syv, syv));
    s_segaux[s] = make_float4(e.x, e.y, d0, d1);
    float i0v = 1.0f / d0;
    float i1v = 1.0f / d1;
    float ryv = sqrtf(__fmul_rn(d1, 0.6971472f)) * 1.00001f;  // outer y radius
    float rxv = sqrtf(__fmul_rn(d0, 0.6971472f)) * 1.00001f;  // outer x radius
    s_segaux2[s] = make_float4(i0v, i1v, ryv, rxv);
  }
}

// Build a seed's 256-px 32-aligned chunk descriptors into s_ck at qoff with a
// seed bit. Wave-redundant (identical-value LDS races benign). Returns chunk
// count, or -1 if appending would overflow CKCAP (nothing written).
__device__ __forceinline__ int build_queue(float cxS, float cyS, float d0S,
    float i1S, float ryS, const int* s_off, unsigned long long* s_ck,
    int lane, int qoff, int sdbit) {
  int r0 = cell_of_y(cyS - ryS);
  int r1 = cell_of_y(cyS + ryS);
  int nr = r1 - r0 + 1;              // <= 19
  int ck = 0, rs_l = 0, re_l = 0, m0_l = 0, m1_l = 0, startl = 0;
  if (lane < nr) {
    int r = r0 + lane;
    float ylo = fmaf((float)r, CELL, -1.0f);
    float dy = fmaxf(0.0f, fmaxf(ylo - cyS, cyS - (ylo + CELL))) * 0.999999f;
    float rem = 0.6971472f - dy * dy * i1S;
    if (rem > 0.0f) {
      float dxm = sqrtf(d0S * rem) * 1.00001f;
      int c0 = cell_of_x(cxS - dxm), c1 = cell_of_x(cxS + dxm);
      int rbase = r * GX;
      rs_l = s_off[rbase + c0]; re_l = s_off[rbase + c1 + 1];
      m0_l = rs_l; m1_l = rs_l;
      float dyc = fmaxf(fabsf(ylo - cyS), fabsf(ylo + CELL - cyS)) + 1e-5f;
      float remI = 0.6920f - dyc * dyc * i1S;
      if (remI > 0.0f) {
        float dxin = sqrtf(d0S * remI) * 0.9999f;
        int a  = (int)ceilf(fmaf(cxS - dxin, INVCELL, INVCELL) + 1e-3f);
        int bb = (int)floorf(fmaf(cxS + dxin, INVCELL, INVCELL) - 1e-3f) - 1;
        a = max(a, c0); bb = min(bb, c1);
        if (a <= bb) { m0_l = s_off[rbase + a]; m1_l = s_off[rbase + bb + 1]; }
      }
      startl = rs_l & ~31;
      ck = (re_l > rs_l) ? ((re_l - startl + 255) >> 8) : 0;
    }
  }
  int cum = wave_scan_incl_i32(ck);
  int ncS = __builtin_amdgcn_readlane(cum, 63);
  if (qoff + ncS > CKCAP) return -1;
  int excl = cum - ck;
  if (lane < nr && ck) {
    for (int k = 0; k < ck; ++k) {
      int i0k = startl + (k << 8);
      int ssk = max(rs_l - i0k, 0);                 // <=31, only k=0 nonzero
      int lok = min(max(m0_l - i0k, 0), 256);
      int h2k = min(max(m1_l - i0k, 0), 256);
      int enk = min(re_l - i0k, 256);
      s_ck[qoff + excl + k] = (unsigned long long)(unsigned)(i0k >> 5)
                     | ((unsigned long long)(unsigned)ssk << 13)
                     | ((unsigned long long)(unsigned)lok << 19)
                     | ((unsigned long long)(unsigned)h2k << 28)
                     | ((unsigned long long)(unsigned)enk << 37)
                     | ((unsigned long long)(unsigned)sdbit << 46);
    }
  }
  return ncS;
}

// One workgroup per image. Seed-PAIRED rounds on the R5 chassis: exact
// per-segment top-2 (ci2-triggered rescans) makes the pairing gate live; when
// the true global 2nd-best seed's outer box is disjoint from the winner's, two
// reference iterations execute in one round over ONE combined chunk queue
// (seed bit per descriptor — no wave split, no imbalance). Disjointness =>
// proposal sets disjoint, claims disjoint, uc/pc independent; labels keep ref
// order. If ucount-ucR0 <= 64 the ref loop stops before iter2: seed2's labels
// are skipped and we break (post-loop state dead, no rollback). Scores are
// sigmoid(seed_raw>0.5) > 0.62, so ref's new_done never fires for any seed.
__global__ __launch_bounds__(1024) void cluster_kernel(const float* __restrict__ in,
                                                       int* __restrict__ out,
                                                       const float2* __restrict__ emb_all,
                                                       const int2* __restrict__ pk_all,
                                                       const int* __restrict__ off_g) {
  __shared__ unsigned int s_uncl[CCAP / 32];            // 24 KB
  __shared__ int s_off[NCELL + 1];                      // 12 KB
  __shared__ unsigned long long s_segkey[NSEGMAX];      // 3 KB
  __shared__ unsigned long long s_segkey2[NSEGMAX];     // 3 KB
  __shared__ int s_segci[NSEGMAX];                      // 1.5 KB
  __shared__ int s_segci2[NSEGMAX];                     // 1.5 KB
  __shared__ float4 s_segaux[NSEGMAX];                  // 6 KB (cx,cy,den0,den1)
  __shared__ float4 s_segaux2[NSEGMAX];                 // 6 KB (inv0,inv1,ry,rx)
  __shared__ int s_dlist[DLCAP];                        // 8 KB
  __shared__ unsigned long long s_ck[CKCAP];            // 12.8 KB packed chunks
  __shared__ ulonglong2 s_ckbA[CKBCAP];                 // 8 KB ballots g0,g1
  __shared__ ulonglong2 s_ckbB[CKBCAP];                 // 8 KB ballots g2,g3
  __shared__ int s_pc4[4];                              // [buf][seed]
  __shared__ int s_uc4[4];
  __shared__ int s_nd[2];

  int b = blockIdx.x;
  int tid = threadIdx.x;
  int lane = tid & 63;
  int wid = tid >> 6;
  const int* offb = off_g + b * (NCELL + 1);
  int V = offb[NCELL];
  const float2* emb = emb_all + (size_t)b * CCAP;
  const int2*   pk  = pk_all  + (size_t)b * CCAP;
  int* outb = out + (size_t)b * NPIX;
  const float* base = in + (size_t)b * 5 * NPIX;

  if (V > CCAP) {   // capacity overflow marker
    for (int i = tid; i < NPIX; i += 1024) outb[i] = 1000000;
    return;
  }
  int NSEG = (V + SEGSZ - 1) >> 9;
  int Vm1 = V - 1;

  for (int i = tid; i <= NCELL; i += 1024) s_off[i] = offb[i];
  for (int w = tid; w < CCAP / 32; w += 1024) {
    int basebit = w << 5;
    unsigned m;
    if (basebit + 32 <= V)      m = 0xffffffffu;
    else if (basebit >= V)      m = 0u;
    else                        m = (1u << (V - basebit)) - 1u;
    s_uncl[w] = m;
  }
  if (tid < 4) { s_pc4[tid] = 0; s_uc4[tid] = 0; }
  if (tid < 2) { s_nd[tid] = 0; }
  __syncthreads();

  // build segment caches (all pixels alive)
  for (int s = wid; s < NSEG; s += 16)
    seg_rescan(s, V, lane, s_uncl, pk, emb, base, s_segkey, s_segkey2,
               s_segci, s_segci2, s_segaux, s_segaux2, false);
  __syncthreads();

  int ucount = V, count = 1, guard = 0;
  int t = 0;
  while (ucount > 64 && guard++ <= CCAP) {
    int cur = t & 1, nxt = cur ^ 1;

    // ---- argmax: lane-local top-2 of segment winners, two u64 DPP reduces ----
    unsigned a1h = 0, a1l = 0, a2h = 0, a2l = 0; int g1 = -1, g2 = -1;
    for (int s = lane; s < NSEG; s += 64) {
      unsigned long long v = s_segkey[s];
      unsigned vh = (unsigned)(v >> 32), vl = (unsigned)v;
      if (vh > a1h || (vh == a1h && vl > a1l)) {
        a2h = a1h; a2l = a1l; g2 = g1; a1h = vh; a1l = vl; g1 = s;
      } else if (vh > a2h || (vh == a2h && vl > a2l)) {
        a2h = vh; a2l = vl; g2 = s;
      }
    }
    unsigned m1h = a1h, m1l = a1l;
    wave_max_key64(m1h, m1l);
    if (m1h == 0u) break;
    bool own1 = (a1h == m1h && a1l == m1l);
    int src1 = __builtin_ctzll(__ballot(own1));
    int sg1 = __shfl(g1, src1);
    unsigned ch = own1 ? a2h : a1h, cl2 = own1 ? a2l : a1l;
    int cg = own1 ? g2 : g1;
    unsigned m2h = ch, m2l = cl2;
    wave_max_key64(m2h, m2l);

    float4 auxA = s_segaux[sg1];
    float4 ax2A = s_segaux2[sg1];
    int kk = 1, sg2 = -1;
    float4 auxB = make_float4(0.f, 0.f, 1.f, 1.f);
    float4 ax2B = make_float4(1.f, 1.f, 0.f, 0.f);
    if (m2h != 0u) {
      bool own2 = (ch == m2h && cl2 == m2l);     // candidate keys distinct
      int src2 = __builtin_ctzll(__ballot(own2));
      sg2 = __shfl(cg, src2);
      unsigned long long k2s = s_segkey2[sg1];   // EXACT 2nd within sg1
      unsigned kh = (unsigned)(k2s >> 32), kl = (unsigned)k2s;
      bool hidden = (kh > m2h) || (kh == m2h && kl > m2l);
      if (!hidden) {                             // m2 IS the global 2nd-best
        auxB = s_segaux[sg2];
        ax2B = s_segaux2[sg2];
        bool ovl = (fabsf(auxA.x - auxB.x) <= (ax2A.w + ax2B.w)) &&
                   (fabsf(auxA.y - auxB.y) <= (ax2A.z + ax2B.z));
        if (!ovl) kk = 2;                        // outer boxes disjoint -> pair
      }
    }

    // ---- combined chunk queue build (wave-redundant, uniform results) ----
    int ncTot = build_queue(auxA.x, auxA.y, auxA.z, ax2A.y, ax2A.z,
                            s_off, s_ck, lane, 0, 0);
    // seed0 alone always fits (worst/seed 792 < CKCAP) -> ncTot >= 0
    if (kk == 2) {
      int nc1 = build_queue(auxB.x, auxB.y, auxB.z, ax2B.y, ax2B.z,
                            s_off, s_ck, lane, ncTot, 1);
      if (nc1 < 0) kk = 1; else ncTot += nc1;
    }

    // ---- pass 1: combined queue, all waves round-robin, 1-deep prefetch ----
    int pc0 = 0, uc0 = 0, pc1 = 0, uc1 = 0;
    int c = wid;
    unsigned long long ed = (c < ncTot) ? s_ck[c] : 0ULL;
    while (c < ncTot) {
      int cn = c + 16;
      unsigned long long epre = (cn < ncTot) ? s_ck[cn] : 0ULL;
      int i0 = ((int)(ed & 0x1fff)) << 5;
      int ss = (int)((ed >> 13) & 0x3f);
      int lo = (int)((ed >> 19) & 0x1ff);
      int h2 = (int)((ed >> 28) & 0x1ff);
      int en = (int)((ed >> 37) & 0x1ff);
      int sb = (int)((ed >> 46) & 1);
      bool interior = (lo <= ss && h2 >= en);
      unsigned long long bm0, bm1, bm2, bm3;
      if (interior) {                   // analytic masks: no loads, no ballots
        bm0 = maskrange64(ss, min(en, 64));
        bm1 = maskrange64(0, min(max(en - 64, 0), 64));
        bm2 = maskrange64(0, min(max(en - 128, 0), 64));
        bm3 = maskrange64(0, min(max(en - 192, 0), 64));
      } else {
        float cx = sb ? auxB.x : auxA.x;
        float cy = sb ? auxB.y : auxA.y;
        float den0 = sb ? auxB.z : auxA.z;
        float den1 = sb ? auxB.w : auxA.w;
        float inv0 = sb ? ax2B.x : ax2A.x;
        float inv1 = sb ? ax2B.y : ax2A.y;
        int idx1 = lane + 64, idx2 = lane + 128, idx3 = lane + 192;
        int ia = min(i0 + lane, Vm1),  ib = min(i0 + idx1, Vm1);
        int ic = min(i0 + idx2, Vm1),  id = min(i0 + idx3, Vm1);
        float2 e0 = emb[ia], e1 = emb[ib], e2 = emb[ic], e3 = emb[id];
        bool t0 = prop_test(e0, cx, cy, den0, den1, inv0, inv1);
        bool t1 = prop_test(e1, cx, cy, den0, den1, inv0, inv1);
        bool t2 = prop_test(e2, cx, cy, den0, den1, inv0, inv1);
        bool t3 = prop_test(e3, cx, cy, den0, den1, inv0, inv1);
        bool p0 = (lane >= ss && lane < en) && ((lane >= lo && lane < h2) || t0);
        bool p1 = (idx1 < en) && ((idx1 >= lo && idx1 < h2) || t1);
        bool p2 = (idx2 < en) && ((idx2 >= lo && idx2 < h2) || t2);
        bool p3 = (idx3 < en) && ((idx3 >= lo && idx3 < h2) || t3);
        bm0 = __ballot(p0);
        bm1 = __ballot(p1);
        bm2 = __ballot(p2);
        bm3 = __ballot(p3);
        if (c < CKBCAP) {
          if (lane == 0)      { ulonglong2 v; v.x = bm0; v.y = bm1; s_ckbA[c] = v; }
          else if (lane == 1) { ulonglong2 v; v.x = bm2; v.y = bm3; s_ckbB[c] = v; }
        }
      }
      if ((bm0 | bm1 | bm2 | bm3) != 0ULL && lane < 8) {
        unsigned long long bsel = (lane < 2) ? bm0 : (lane < 4) ? bm1
                                 : (lane < 6) ? bm2 : bm3;
        unsigned bits = (unsigned)(bsel >> ((lane & 1) << 5));
        int add = __popc(bits);
        if (sb) pc1 += add; else pc0 += add;
        if (bits) {
          unsigned tw = (unsigned)(i0 >> 5) + (unsigned)lane;
          unsigned old = atomicAnd(&s_uncl[tw], ~bits);
          unsigned remv = old & bits;
          if (remv) {
            int radd = __popc(remv);
            if (sb) uc1 += radd; else uc0 += radd;
            int seg = (int)(tw >> 4);           // 512 px = 16 words
            int ciw = s_segci[seg];
            int ciw2 = s_segci2[seg];
            bool hit = ((ciw  >> 5) == (int)tw && ((remv >> (ciw  & 31)) & 1u)) ||
                       ((ciw2 >> 5) == (int)tw && ((remv >> (ciw2 & 31)) & 1u));
            if (hit) {
              int pos = atomicAdd(&s_nd[cur], 1);
              if (pos < DLCAP) s_dlist[pos] = seg;
            }
          }
        }
      }
      c = cn; ed = epre;
    }
    {
      int pcW = wave_sum_bcast_i32(pc0);
      int ucW = wave_sum_bcast_i32(uc0);
      if (lane == 0 && (pcW | ucW)) {
        if (pcW) atomicAdd(&s_pc4[cur * 2 + 0], pcW);
        if (ucW) atomicAdd(&s_uc4[cur * 2 + 0], ucW);
      }
      if (kk == 2) {
        int pcW1 = wave_sum_bcast_i32(pc1);
        int ucW1 = wave_sum_bcast_i32(uc1);
        if (lane == 0 && (pcW1 | ucW1)) {
          if (pcW1) atomicAdd(&s_pc4[cur * 2 + 1], pcW1);
          if (ucW1) atomicAdd(&s_uc4[cur * 2 + 1], ucW1);
        }
      }
    }
    __syncthreads();   // B1

    int pcT0 = s_pc4[cur * 2 + 0], ucR0 = s_uc4[cur * 2 + 0];
    int pcT1 = s_pc4[cur * 2 + 1], ucR1 = s_uc4[cur * 2 + 1];
    int ndRaw = s_nd[cur];
    bool acc0 = (pcT0 > 64) && (2 * (ucR0 - 1) > pcT0);  // ref uc excludes seed
    bool valid1 = (kk == 2) && (ucount - ucR0 > 64);     // ref loop-cond at iter2
    bool acc1 = valid1 && (pcT1 > 64) && (2 * (ucR1 - 1) > pcT1);
    int label0 = count & 255; if (acc0) count++;
    int label1 = count & 255; if (acc1) count++;
    ucount -= ucR0;
    if (valid1) ucount -= ucR1;
    if (tid == 0) {
      s_pc4[nxt * 2] = 0; s_pc4[nxt * 2 + 1] = 0;
      s_uc4[nxt * 2] = 0; s_uc4[nxt * 2 + 1] = 0;
      s_nd[nxt] = 0;
    }

    // ---- labels (only accepted seeds) — combined queue, seed bit selects ----
    if (acc0 || acc1) {
      for (int c2 = wid; c2 < ncTot; c2 += 16) {
        unsigned long long e = s_ck[c2];
        int sb = (int)((e >> 46) & 1);
        bool acc = sb ? acc1 : acc0;
        if (!acc) continue;
        int label = sb ? label1 : label0;
        int i0 = ((int)(e & 0x1fff)) << 5;
        int ss = (int)((e >> 13) & 0x3f);
        int lo = (int)((e >> 19) & 0x1ff);
        int h2 = (int)((e >> 28) & 0x1ff);
        int en = (int)((e >> 37) & 0x1ff);
        bool interior = (lo <= ss && h2 >= en);
        if (interior) {                 // analytic replay: no loads, no tests
          unsigned long long b0 = maskrange64(ss, min(en, 64));
          unsigned long long b1 = maskrange64(0, min(max(en - 64, 0), 64));
          unsigned long long b2 = maskrange64(0, min(max(en - 128, 0), 64));
          unsigned long long b3 = maskrange64(0, min(max(en - 192, 0), 64));
          if ((b0 >> lane) & 1ULL) outb[pk[i0 + lane].y] = label;
          if ((b1 >> lane) & 1ULL) outb[pk[i0 + 64 + lane].y] = label;
          if ((b2 >> lane) & 1ULL) outb[pk[i0 + 128 + lane].y] = label;
          if ((b3 >> lane) & 1ULL) outb[pk[i0 + 192 + lane].y] = label;
        } else if (c2 < CKBCAP) {       // cached-ballot replay
          ulonglong2 ba = s_ckbA[c2];
          ulonglong2 bb = s_ckbB[c2];
          if ((ba.x >> lane) & 1ULL) outb[pk[i0 + lane].y] = label;
          if ((ba.y >> lane) & 1ULL) outb[pk[i0 + 64 + lane].y] = label;
          if ((bb.x >> lane) & 1ULL) outb[pk[i0 + 128 + lane].y] = label;
          if ((bb.y >> lane) & 1ULL) outb[pk[i0 + 192 + lane].y] = label;
        } else {                        // overflow chunks: recompute
          float cx = sb ? auxB.x : auxA.x;
          float cy = sb ? auxB.y : auxA.y;
          float den0 = sb ? auxB.z : auxA.z;
          float den1 = sb ? auxB.w : auxA.w;
          float inv0 = sb ? ax2B.x : ax2A.x;
          float inv1 = sb ? ax2B.y : ax2A.y;
          #pragma unroll
          for (int g = 0; g < 4; ++g) {
            int idx = (g << 6) + lane;
            if (idx >= ss && idx < en &&
                ((idx >= lo && idx < h2) ||
                 prop_test(emb[i0 + idx], cx, cy, den0, den1, inv0, inv1)))
              outb[pk[i0 + idx].y] = label;
          }
        }
      }
    }

    // ref loop would have stopped before iter2: state is dead, just exit.
    if (kk == 2 && !valid1) break;

    // ---- rescans: segments whose cached top-2 member was removed ----
    if (ndRaw > DLCAP) {
      for (int s = wid; s < NSEG; s += 16)
        seg_rescan(s, V, lane, s_uncl, pk, emb, base, s_segkey, s_segkey2,
                   s_segci, s_segci2, s_segaux, s_segaux2, true);
    } else {
      for (int d = wid; d < ndRaw; d += 16)
        seg_rescan(s_dlist[d], V, lane, s_uncl, pk, emb, base, s_segkey,
                   s_segkey2, s_segci, s_segci2, s_segaux, s_segaux2, true);
    }
    __syncthreads();   // B2
    t++;
  }
}

// ---------------- launch ----------------

extern "C" void kernel_launch(void* const* d_in, const int* in_sizes, int n_in,
                              void* d_out, int out_size, void* d_ws, size_t ws_size,
                              hipStream_t stream) {
  const float* in = (const float*)d_in[0];
  int* out = (int*)d_out;

  size_t hist_bytes = (size_t)BATCH * NCELL * sizeof(int);
  size_t off_bytes  = (size_t)BATCH * (NCELL + 1) * sizeof(int);
  size_t cur_bytes  = (size_t)BATCH * NCELL * sizeof(int);
  size_t emb_bytes  = (size_t)BATCH * CCAP * sizeof(float2);
  size_t pk_bytes   = (size_t)BATCH * CCAP * sizeof(int2);

  size_t o_hist = 256;
  size_t o_off  = (o_hist + hist_bytes + 255) & ~(size_t)255;
  size_t o_cur  = (o_off + off_bytes + 255) & ~(size_t)255;
  size_t o_emb  = (o_cur + cur_bytes + 255) & ~(size_t)255;
  size_t o_pk   = (o_emb + emb_bytes + 255) & ~(size_t)255;
  size_t need   = o_pk + pk_bytes;

  if (ws_size < need) {
    fill_kernel<<<(out_size + 1023) / 1024, 1024, 0, stream>>>(out, 2000000, out_size);
    return;
  }

  int*    hist = (int*)((char*)d_ws + o_hist);
  int*    off  = (int*)((char*)d_ws + o_off);
  int*    cur  = (int*)((char*)d_ws + o_cur);
  float2* emb  = (float2*)((char*)d_ws + o_emb);
  int2*   pk   = (int2*)((char*)d_ws + o_pk);

  hipMemsetAsync(hist, 0, hist_bytes, stream);
  hist_kernel<<<(BATCH * NPIX) / 1024, 1024, 0, stream>>>(in, out, hist);
  scan_kernel<<<BATCH, 1024, 0, stream>>>(hist, off, cur);
  scatter_kernel<<<(BATCH * NPIX) / 1024, 1024, 0, stream>>>(in, cur, emb, pk);
  cluster_kernel<<<BATCH, 1024, 0, stream>>>(in, out, emb, pk, off);
}

// Round 7
// 793.412 us; speedup vs baseline: 1.1849x; 1.1849x over previous
//
#include <hip/hip_runtime.h>
#include <math.h>

#define BATCH 4
#define HH 512
#define WW 1024
#define NPIX (HH*WW)          // 524288 = 2^19
#define CCAP 196608           // compaction capacity per image (expected ~161.7k valid)
#define GX 64
#define GY 48
#define NCELL (GX*GY)         // 3072 cells, 0.0625 x 0.0625 over [-1,3]x[-1,2]
#define CELL 0.0625f
#define INVCELL 16.0f
#define SEGSZ 512             // pixels per argmax-cache segment
#define NSEGMAX (CCAP/SEGSZ)  // 384
#define DLCAP 2048            // dirty-segment list capacity
#define CKCAP 800             // 256-px chunk queue capacity (worst case 792)
#define CKBCAP 512            // chunks with cached proposal ballot bits

// ---------------- XLA:CPU f32 math replicas (unchanged from passing rounds) ----
__device__ __forceinline__ float xla_tanhf(float x) {
  if (fabsf(x) < 0.0004f) return x;
  float xc = fminf(fmaxf(x, -7.90531110763549805f), 7.90531110763549805f);
  float x2 = __fmul_rn(xc, xc);
  float p = -2.76076847742355e-16f;
  p = fmaf(x2, p, 2.00018790482477e-13f);
  p = fmaf(x2, p, -8.60467152213735e-11f);
  p = fmaf(x2, p, 5.12229709037114e-08f);
  p = fmaf(x2, p, 1.48572235717979e-05f);
  p = fmaf(x2, p, 6.37261928875436e-04f);
  p = fmaf(x2, p, 4.89352455891786e-03f);
  p = __fmul_rn(xc, p);
  float q = fmaf(x2, 1.19825839466702e-06f, 1.18534705686654e-04f);
  q = fmaf(x2, q, 2.26843463243900e-03f);
  q = fmaf(x2, q, 4.89352518554385e-03f);
  return __fdiv_rn(p, q);
}

__device__ __forceinline__ float xla_expf(float x) {
  float xc = fminf(fmaxf(x, -87.3365478515625f), 88.72283935546875f);
  float m = floorf(fmaf(xc, 1.44269504088896341f, 0.5f));
  float r = fmaf(m, -0.693359375f, xc);
  r = fmaf(m, 2.12194440e-4f, r);
  float r2 = __fmul_rn(r, r);
  float p = 1.9875691500e-4f;
  p = fmaf(p, r, 1.3981999507e-3f);
  p = fmaf(p, r, 8.3334519073e-3f);
  p = fmaf(p, r, 4.1665795894e-2f);
  p = fmaf(p, r, 1.6666665459e-1f);
  p = fmaf(p, r, 5.0000001201e-1f);
  float y = fmaf(r2, p, r);
  y = __fadd_rn(y, 1.0f);
  return ldexpf(y, (int)m);
}

__device__ __forceinline__ float xla_sigmoidf(float x) {
  return fmaf(0.5f, xla_tanhf(__fmul_rn(0.5f, x)), 0.5f);
}

// Proposal test — byte-identical decision logic to the passing kernels.
__device__ __forceinline__ bool prop_test(float2 e, float cx, float cy,
                                          float den0, float den1,
                                          float inv0, float inv1) {
  float d0 = __fsub_rn(e.x, cx), d1 = __fsub_rn(e.y, cy);
  float dd0 = __fmul_rn(d0, d0), dd1 = __fmul_rn(d1, d1);
  float zf = fmaf(dd0, inv0, __fmul_rn(dd1, inv1));
  if (zf < 0.6921472f) return true;
  if (zf <= 0.6941472f) {
    float t0 = __fdiv_rn(dd0, den0);
    float t1 = __fdiv_rn(dd1, den1);
    float z = __fadd_rn(t0, t1);
    return xla_expf(-z) > 0.5f;
  }
  return false;
}

__device__ __forceinline__ int cell_of_x(float ex) {
  int c = (int)((ex + 1.0f) * INVCELL);
  return min(max(c, 0), GX - 1);
}
__device__ __forceinline__ int cell_of_y(float ey) {
  int c = (int)((ey + 1.0f) * INVCELL);
  return min(max(c, 0), GY - 1);
}

// bits [a,b) of a 64-bit mask; requires 0 <= a < 64, 0 <= b <= 64, a <= b.
__device__ __forceinline__ unsigned long long maskrange64(int a, int b) {
  unsigned long long mb = (b >= 64) ? ~0ULL : ((1ULL << b) - 1ULL);
  unsigned long long ma = (1ULL << a) - 1ULL;
  return mb & ~ma;
}

// ---------------- DPP wave64 primitives (VALU-speed, replaces DS shfl chains) --
// Standard rocPRIM sequence: row_shr 1/2/4/8 then row_bcast15 (rows 1,3) and
// row_bcast31 (rows 2,3). Reduce result lands in lane 63; readlane broadcasts.
__device__ __forceinline__ unsigned wave_max_bcast_u32(unsigned x) {
  unsigned t;
  t = (unsigned)__builtin_amdgcn_update_dpp(0, (int)x, 0x111, 0xf, 0xf, false); if (t > x) x = t;
  t = (unsigned)__builtin_amdgcn_update_dpp(0, (int)x, 0x112, 0xf, 0xf, false); if (t > x) x = t;
  t = (unsigned)__builtin_amdgcn_update_dpp(0, (int)x, 0x114, 0xf, 0xf, false); if (t > x) x = t;
  t = (unsigned)__builtin_amdgcn_update_dpp(0, (int)x, 0x118, 0xf, 0xf, false); if (t > x) x = t;
  t = (unsigned)__builtin_amdgcn_update_dpp(0, (int)x, 0x142, 0xa, 0xf, false); if (t > x) x = t;
  t = (unsigned)__builtin_amdgcn_update_dpp(0, (int)x, 0x143, 0xc, 0xf, false); if (t > x) x = t;
  return (unsigned)__builtin_amdgcn_readlane((int)x, 63);
}

__device__ __forceinline__ int wave_sum_bcast_i32(int x) {
  x += __builtin_amdgcn_update_dpp(0, x, 0x111, 0xf, 0xf, false);
  x += __builtin_amdgcn_update_dpp(0, x, 0x112, 0xf, 0xf, false);
  x += __builtin_amdgcn_update_dpp(0, x, 0x114, 0xf, 0xf, false);
  x += __builtin_amdgcn_update_dpp(0, x, 0x118, 0xf, 0xf, false);
  x += __builtin_amdgcn_update_dpp(0, x, 0x142, 0xa, 0xf, false);
  x += __builtin_amdgcn_update_dpp(0, x, 0x143, 0xc, 0xf, false);
  return __builtin_amdgcn_readlane(x, 63);
}

__device__ __forceinline__ int wave_scan_incl_i32(int x) {   // per-lane inclusive
  x += __builtin_amdgcn_update_dpp(0, x, 0x111, 0xf, 0xf, false);
  x += __builtin_amdgcn_update_dpp(0, x, 0x112, 0xf, 0xf, false);
  x += __builtin_amdgcn_update_dpp(0, x, 0x114, 0xf, 0xf, false);
  x += __builtin_amdgcn_update_dpp(0, x, 0x118, 0xf, 0xf, false);
  x += __builtin_amdgcn_update_dpp(0, x, 0x142, 0xa, 0xf, false);
  x += __builtin_amdgcn_update_dpp(0, x, 0x143, 0xc, 0xf, false);
  return x;
}

// ---------------- kernels ----------------

__global__ __launch_bounds__(1024) void fill_kernel(int* out, int val, int n) {
  int i = blockIdx.x * 1024 + threadIdx.x;
  if (i < n) out[i] = val;
}

// pass A: zero output, LDS-aggregated histogram (one global atomic per block+cell)
__global__ __launch_bounds__(1024) void hist_kernel(const float* __restrict__ in,
                                                    int* __restrict__ out,
                                                    int* __restrict__ hist) {
  __shared__ int lh[NCELL];
  int tid = threadIdx.x;
  int gid = blockIdx.x * 1024 + tid;
  int b = gid >> 19;
  int p = gid & (NPIX - 1);
  for (int j = tid; j < NCELL; j += 1024) lh[j] = 0;
  __syncthreads();
  const float* base = in + (size_t)b * 5 * NPIX;
  float seed = base[(size_t)4 * NPIX + p];
  out[gid] = 0;
  if (seed > 0.5f) {
    float ox = base[p];
    float oy = base[(size_t)NPIX + p];
    int col = p & (WW - 1);
    int row = p >> 10;
    float gx = __fmul_rn((float)col, 2.0f / 1023.0f);
    float gy = __fmul_rn((float)row, 1.0f / 511.0f);
    float ex = __fadd_rn(xla_tanhf(ox), gx);
    float ey = __fadd_rn(xla_tanhf(oy), gy);
    atomicAdd(&lh[cell_of_y(ey) * GX + cell_of_x(ex)], 1);
  }
  __syncthreads();
  for (int j = tid; j < NCELL; j += 1024) {
    int c = lh[j];
    if (c) atomicAdd(&hist[b * NCELL + j], c);
  }
}

// pass B: exclusive scan of the cell counts per image (one block per image)
__global__ __launch_bounds__(1024) void scan_kernel(const int* __restrict__ hist,
                                                    int* __restrict__ off,
                                                    int* __restrict__ cursor) {
  __shared__ int s_c[NCELL];
  __shared__ int s_ps[1024];
  int b = blockIdx.x, t = threadIdx.x;
  const int* h = hist + b * NCELL;
  for (int i = t; i < NCELL; i += 1024) s_c[i] = h[i];
  __syncthreads();
  int a = s_c[3 * t], b2 = s_c[3 * t + 1], c2 = s_c[3 * t + 2];
  int th = a + b2 + c2;
  s_ps[t] = th;
  __syncthreads();
  for (int d = 1; d < 1024; d <<= 1) {
    int v = (t >= d) ? s_ps[t - d] : 0;
    __syncthreads();
    s_ps[t] += v;
    __syncthreads();
  }
  int excl = s_ps[t] - th;
  int* ob = off + b * (NCELL + 1);
  int* cb = cursor + b * NCELL;
  ob[3 * t] = excl;              cb[3 * t] = excl;
  ob[3 * t + 1] = excl + a;      cb[3 * t + 1] = excl + a;
  ob[3 * t + 2] = excl + a + b2; cb[3 * t + 2] = excl + a + b2;
  if (t == 1023) ob[NCELL] = s_ps[1023];
}

// pass C: LDS-aggregated scatter (within-cell order arbitrary; downstream is
// order-independent, tiebreak uses global pixel index)
__global__ __launch_bounds__(1024) void scatter_kernel(const float* __restrict__ in,
                                                       int* __restrict__ cursor,
                                                       float2* __restrict__ emb,
                                                       int2* __restrict__ pk) {
  __shared__ int lh[NCELL];
  __shared__ int lbase[NCELL];
  int tid = threadIdx.x;
  int gid = blockIdx.x * 1024 + tid;
  int b = gid >> 19;
  int p = gid & (NPIX - 1);
  for (int j = tid; j < NCELL; j += 1024) lh[j] = 0;
  __syncthreads();
  const float* base = in + (size_t)b * 5 * NPIX;
  float seed = base[(size_t)4 * NPIX + p];
  bool valid = seed > 0.5f;
  float ex = 0.0f, ey = 0.0f, smv = 0.0f;
  int cell = 0, sl = 0;
  if (valid) {
    float ox = base[p];
    float oy = base[(size_t)NPIX + p];
    int col = p & (WW - 1);
    int row = p >> 10;
    float gx = __fmul_rn((float)col, 2.0f / 1023.0f);
    float gy = __fmul_rn((float)row, 1.0f / 511.0f);
    ex = __fadd_rn(xla_tanhf(ox), gx);
    ey = __fadd_rn(xla_tanhf(oy), gy);
    smv = xla_sigmoidf(seed);
    cell = cell_of_y(ey) * GX + cell_of_x(ex);
    sl = atomicAdd(&lh[cell], 1);
  }
  __syncthreads();
  for (int j = tid; j < NCELL; j += 1024) {
    int c = lh[j];
    if (c) lbase[j] = atomicAdd(&cursor[b * NCELL + j], c);
  }
  __syncthreads();
  if (valid) {
    int slot = lbase[cell] + sl;
    if (slot < CCAP) {
      emb[(size_t)b * CCAP + slot] = make_float2(ex, ey);
      pk[(size_t)b * CCAP + slot]  = make_int2(__float_as_int(smv), p);
    }
  }
}

// Segment scan helper (SEGSZ=512: 8 strips of 64). DPP 32-bit-score reduce
// (exact 64-bit shfl fallback on score ties — keys are globally unique via
// ~pixel-index low bits). The unique winner lane precomputes reciprocal/radius
// aux2 so the broadcast path after argmax has no div/sqrt.
__device__ __forceinline__ void seg_rescan(int s, int V, int lane,
    const unsigned* s_uncl, const int2* __restrict__ pk,
    const float2* __restrict__ emb, const float* __restrict__ base,
    unsigned long long* s_segkey, int* s_segci, float4* s_segaux,
    float4* s_segaux2, bool checkAlive) {
  unsigned long long bk = 0ULL; int bci = -1; int bpx = 0;
  #pragma unroll
  for (int j = 0; j < 8; ++j) {
    int i = (s << 9) + (j << 6) + lane;
    if (i < V) {
      bool alive = !checkAlive || ((s_uncl[i >> 5] >> (i & 31)) & 1u);
      if (alive) {
        int2 v = pk[i];
        unsigned long long k = ((unsigned long long)(unsigned)v.x << 32) | (unsigned)(~v.y);
        if (k > bk) { bk = k; bci = i; bpx = v.y; }
      }
    }
  }
  unsigned bs = (unsigned)(bk >> 32);
  unsigned ms = wave_max_bcast_u32(bs);
  if (ms == 0u) {                       // segment fully dead
    if (lane == 0) { s_segkey[s] = 0ULL; s_segci[s] = -1; }
    return;
  }
  unsigned long long tie = __ballot(bs == ms);
  bool winner;
  if (__popcll(tie) == 1ULL) {
    winner = (bs == ms);
  } else {
    unsigned long long mk = bk;
    #pragma unroll
    for (int o = 1; o < 64; o <<= 1) {
      unsigned long long ok = __shfl_xor(mk, o);
      if (ok > mk) mk = ok;
    }
    winner = (bk == mk);                // keys unique -> exactly one lane
  }
  if (winner) {
    s_segkey[s] = bk; s_segci[s] = bci;
    float2 e = emb[bci];
    float sxv = base[(size_t)2 * NPIX + bpx];
    float syv = base[(size_t)3 * NPIX + bpx];
    float d0 = __fmul_rn(2.0f, __fmul_rn(sxv, sxv));   // ref: 2.0 * s**2
    float d1 = __fmul_rn(2.0f, __fmul_rn(syv, syv));
    s_segaux[s] = make_float4(e.x, e.y, d0, d1);
    float i0v = 1.0f / d0;              // same expr as old broadcast path
    float i1v = 1.0f / d1;
    float ryv = sqrtf(__fmul_rn(d1, 0.6971472f)) * 1.00001f;
    s_segaux2[s] = make_float4(i0v, i1v, ryv, 0.0f);
  }
}

// One workgroup per image. 2 barriers/iteration. Pass-1 work is a flat 256-px
// 32-aligned chunk queue of packed u64 descriptors
// {i0>>5 | ss<<13 | lo<<19 | h2<<28 | en<<37} (chunk-relative clamped bounds;
// [ss,en) is this chunk's owned pixel range). Queue built redundantly per wave
// (benign identical-value LDS races), consumed round-robin by all 16 waves
// with 1-deep descriptor prefetch. Interior chunks (lo<=ss && h2>=en) use
// ANALYTIC range masks — no loads, no ballots, no ballot-cache; the label
// pass re-derives their masks from the descriptor. Boundary-chunk ballots
// are cached in split arrays (s_ckbA/s_ckbB) for label replay.
__global__ __launch_bounds__(1024) void cluster_kernel(const float* __restrict__ in,
                                                       int* __restrict__ out,
                                                       const float2* __restrict__ emb_all,
                                                       const int2* __restrict__ pk_all,
                                                       const int* __restrict__ off_g) {
  __shared__ unsigned int s_uncl[CCAP / 32];            // 24 KB
  __shared__ int s_off[NCELL + 1];                      // 12 KB
  __shared__ unsigned long long s_segkey[NSEGMAX];      // 3 KB
  __shared__ int s_segci[NSEGMAX];                      // 1.5 KB
  __shared__ float4 s_segaux[NSEGMAX];                  // 6 KB
  __shared__ float4 s_segaux2[NSEGMAX];                 // 6 KB (inv0,inv1,ry)
  __shared__ int s_dlist[DLCAP];                        // 8 KB
  __shared__ unsigned long long s_ck[CKCAP];            // 6.4 KB packed chunks
  __shared__ ulonglong2 s_ckbA[CKBCAP];                 // 8 KB ballots g0,g1
  __shared__ ulonglong2 s_ckbB[CKBCAP];                 // 8 KB ballots g2,g3
  __shared__ int s_pc[2];
  __shared__ int s_uc[2];
  __shared__ int s_nd[2];

  int b = blockIdx.x;
  int tid = threadIdx.x;
  int lane = tid & 63;
  int wid = tid >> 6;
  const int* offb = off_g + b * (NCELL + 1);
  int V = offb[NCELL];
  const float2* emb = emb_all + (size_t)b * CCAP;
  const int2*   pk  = pk_all  + (size_t)b * CCAP;
  int* outb = out + (size_t)b * NPIX;
  const float* base = in + (size_t)b * 5 * NPIX;

  if (V > CCAP) {   // capacity overflow marker
    for (int i = tid; i < NPIX; i += 1024) outb[i] = 1000000;
    return;
  }
  int NSEG = (V + SEGSZ - 1) >> 9;
  int Vm1 = V - 1;

  for (int i = tid; i <= NCELL; i += 1024) s_off[i] = offb[i];
  for (int w = tid; w < CCAP / 32; w += 1024) {
    int basebit = w << 5;
    unsigned m;
    if (basebit + 32 <= V)      m = 0xffffffffu;
    else if (basebit >= V)      m = 0u;
    else                        m = (1u << (V - basebit)) - 1u;
    s_uncl[w] = m;
  }
  if (tid < 2) { s_pc[tid] = 0; s_uc[tid] = 0; s_nd[tid] = 0; }
  __syncthreads();

  // build segment caches (all pixels alive)
  for (int s = wid; s < NSEG; s += 16)
    seg_rescan(s, V, lane, s_uncl, pk, emb, base, s_segkey, s_segci, s_segaux,
               s_segaux2, false);
  __syncthreads();

  int ucount = V, count = 1, guard = 0;
  int t = 0;
  while (ucount > 64 && guard++ <= CCAP) {
    int cur = t & 1, nxt = cur ^ 1;

    // ---- wave-redundant argmax: DPP 32-bit score reduce + ballot recovery ----
    unsigned long long lk = 0ULL; int lsg = -1;
    for (int s = lane; s < NSEG; s += 64) {
      unsigned long long v = s_segkey[s];
      if (v > lk) { lk = v; lsg = s; }
    }
    unsigned ls = (unsigned)(lk >> 32);
    unsigned gs = wave_max_bcast_u32(ls);
    if (gs == 0u) break;
    float sm = __uint_as_float(gs);
    if (sm < 0.5f) break;              // ref's new_done (provably never fires)
    unsigned long long bmask = __ballot(ls == gs);
    int src, sg;
    if (__popcll(bmask) == 1ULL) {     // unique score -> that lane's key is max
      src = __builtin_ctzll(bmask);
      sg = __shfl(lsg, src);
    } else {                           // score tie: exact 64-bit fallback
      unsigned long long gk = lk;
      #pragma unroll
      for (int o = 1; o < 64; o <<= 1) {
        unsigned long long ok = __shfl_xor(gk, o);
        if (ok > gk) gk = ok;
      }
      unsigned long long bm2 = __ballot(lk == gk);   // keys unique -> one lane
      src = __builtin_ctzll(bm2);
      sg = __shfl(lsg, src);
    }

    float4 aux = s_segaux[sg];         // broadcast LDS reads
    float4 ax2 = s_segaux2[sg];
    float cx = aux.x, cy = aux.y, den0 = aux.z, den1 = aux.w;
    float inv0 = ax2.x;
    float inv1 = ax2.y;
    float ry = ax2.z;
    int r0 = cell_of_y(cy - ry);
    int r1 = cell_of_y(cy + ry);
    int nr = r1 - r0 + 1;              // <= 19

    // ---- per-lane row geometry + packed chunk queue build (redundant) ----
    int ck = 0, rs_l = 0, re_l = 0, m0_l = 0, m1_l = 0, startl = 0;
    if (lane < nr) {
      int r = r0 + lane;
      float ylo = fmaf((float)r, CELL, -1.0f);
      float dy = fmaxf(0.0f, fmaxf(ylo - cy, cy - (ylo + CELL))) * 0.999999f;
      float rem = 0.6971472f - dy * dy * inv1;
      if (rem > 0.0f) {
        float dxm = sqrtf(den0 * rem) * 1.00001f;
        int c0 = cell_of_x(cx - dxm), c1 = cell_of_x(cx + dxm);
        int rbase = r * GX;
        rs_l = s_off[rbase + c0]; re_l = s_off[rbase + c1 + 1];
        m0_l = rs_l; m1_l = rs_l;
        float dyc = fmaxf(fabsf(ylo - cy), fabsf(ylo + CELL - cy)) + 1e-5f;
        float remI = 0.6920f - dyc * dyc * inv1;
        if (remI > 0.0f) {
          float dxin = sqrtf(den0 * remI) * 0.9999f;
          int a  = (int)ceilf(fmaf(cx - dxin, INVCELL, INVCELL) + 1e-3f);
          int bb = (int)floorf(fmaf(cx + dxin, INVCELL, INVCELL) - 1e-3f) - 1;
          a = max(a, c0); bb = min(bb, c1);
          if (a <= bb) { m0_l = s_off[rbase + a]; m1_l = s_off[rbase + bb + 1]; }
        }
        startl = rs_l & ~31;
        ck = (re_l > rs_l) ? ((re_l - startl + 255) >> 8) : 0;
      }
    }
    int cum = wave_scan_incl_i32(ck);   // DPP inclusive scan (lanes>=nr add 0)
    int nc = __builtin_amdgcn_readlane(cum, 63);
    int excl = cum - ck;
    if (lane < nr && ck) {
      for (int k = 0; k < ck; ++k) {
        int i0k = startl + (k << 8);
        int ssk = max(rs_l - i0k, 0);                 // <=31, only k=0 nonzero
        int lok = min(max(m0_l - i0k, 0), 256);
        int h2k = min(max(m1_l - i0k, 0), 256);
        int enk = min(re_l - i0k, 256);
        s_ck[excl + k] = (unsigned long long)(unsigned)(i0k >> 5)
                       | ((unsigned long long)(unsigned)ssk << 13)
                       | ((unsigned long long)(unsigned)lok << 19)
                       | ((unsigned long long)(unsigned)h2k << 28)
                       | ((unsigned long long)(unsigned)enk << 37);
      }
    }

    // ---- pass 1: chunk queue, all waves round-robin, 1-deep prefetch ----
    int pc = 0, uc = 0;
    int c = wid;
    unsigned long long ed = (c < nc) ? s_ck[c] : 0ULL;
    while (c < nc) {
      int cn = c + 16;
      unsigned long long epre = (cn < nc) ? s_ck[cn] : 0ULL;
      int i0 = ((int)(ed & 0x1fff)) << 5;
      int ss = (int)((ed >> 13) & 0x3f);
      int lo = (int)((ed >> 19) & 0x1ff);
      int h2 = (int)((ed >> 28) & 0x1ff);
      int en = (int)((ed >> 37) & 0x1ff);
      bool interior = (lo <= ss && h2 >= en);
      unsigned long long bm0, bm1, bm2, bm3;
      if (interior) {                   // analytic masks: no loads, no ballots
        bm0 = maskrange64(ss, min(en, 64));
        bm1 = maskrange64(0, min(max(en - 64, 0), 64));
        bm2 = maskrange64(0, min(max(en - 128, 0), 64));
        bm3 = maskrange64(0, min(max(en - 192, 0), 64));
      } else {
        int idx1 = lane + 64, idx2 = lane + 128, idx3 = lane + 192;
        int ia = min(i0 + lane, Vm1),  ib = min(i0 + idx1, Vm1);
        int ic = min(i0 + idx2, Vm1),  id = min(i0 + idx3, Vm1);
        float2 e0 = emb[ia], e1 = emb[ib], e2 = emb[ic], e3 = emb[id];
        bool t0 = prop_test(e0, cx, cy, den0, den1, inv0, inv1);
        bool t1 = prop_test(e1, cx, cy, den0, den1, inv0, inv1);
        bool t2 = prop_test(e2, cx, cy, den0, den1, inv0, inv1);
        bool t3 = prop_test(e3, cx, cy, den0, den1, inv0, inv1);
        bool p0 = (lane >= ss && lane < en) && ((lane >= lo && lane < h2) || t0);
        bool p1 = (idx1 < en) && ((idx1 >= lo && idx1 < h2) || t1);
        bool p2 = (idx2 < en) && ((idx2 >= lo && idx2 < h2) || t2);
        bool p3 = (idx3 < en) && ((idx3 >= lo && idx3 < h2) || t3);
        bm0 = __ballot(p0);
        bm1 = __ballot(p1);
        bm2 = __ballot(p2);
        bm3 = __ballot(p3);
        if (c < CKBCAP) {
          if (lane == 0)      { ulonglong2 v; v.x = bm0; v.y = bm1; s_ckbA[c] = v; }
          else if (lane == 1) { ulonglong2 v; v.x = bm2; v.y = bm3; s_ckbB[c] = v; }
        }
      }
      if ((bm0 | bm1 | bm2 | bm3) != 0ULL && lane < 8) {
        unsigned long long bsel = (lane < 2) ? bm0 : (lane < 4) ? bm1
                                 : (lane < 6) ? bm2 : bm3;
        unsigned bits = (unsigned)(bsel >> ((lane & 1) << 5));
        pc += __popc(bits);
        if (bits) {
          unsigned tw = (unsigned)(i0 >> 5) + (unsigned)lane;
          unsigned old = atomicAnd(&s_uncl[tw], ~bits);
          unsigned remv = old & bits;
          if (remv) {
            uc += __popc(remv);
            int seg = (int)(tw >> 4);           // 512 px = 16 words
            int ciw = s_segci[seg];
            if ((ciw >> 5) == (int)tw && ((remv >> (ciw & 31)) & 1u)) {
              int pos = atomicAdd(&s_nd[cur], 1);
              if (pos < DLCAP) s_dlist[pos] = seg;
            }
          }
        }
      }
      c = cn; ed = epre;
    }
    int pcW = wave_sum_bcast_i32(pc);
    int ucW = wave_sum_bcast_i32(uc);
    if (lane == 0 && (pcW | ucW)) {
      if (pcW) atomicAdd(&s_pc[cur], pcW);
      if (ucW) atomicAdd(&s_uc[cur], ucW);
    }
    __syncthreads();   // B1

    int pcT = s_pc[cur];
    int ucR = s_uc[cur];            // total removed this iter (includes seed)
    int ndRaw = s_nd[cur];
    bool accept = (pcT > 64) && (2 * (ucR - 1) > pcT);  // ref uc excludes seed
    int label = count & 255;
    if (accept) count++;
    ucount -= ucR;
    if (tid == 0) { s_pc[nxt] = 0; s_uc[nxt] = 0; s_nd[nxt] = 0; }

    // ---- labels (rare: only accepted iterations) ----
    if (accept) {
      for (int c2 = wid; c2 < nc; c2 += 16) {
        unsigned long long e = s_ck[c2];
        int i0 = ((int)(e & 0x1fff)) << 5;
        int ss = (int)((e >> 13) & 0x3f);
        int lo = (int)((e >> 19) & 0x1ff);
        int h2 = (int)((e >> 28) & 0x1ff);
        int en = (int)((e >> 37) & 0x1ff);
        bool interior = (lo <= ss && h2 >= en);
        if (interior) {                 // analytic replay: no loads, no tests
          unsigned long long b0 = maskrange64(ss, min(en, 64));
          unsigned long long b1 = maskrange64(0, min(max(en - 64, 0), 64));
          unsigned long long b2 = maskrange64(0, min(max(en - 128, 0), 64));
          unsigned long long b3 = maskrange64(0, min(max(en - 192, 0), 64));
          if ((b0 >> lane) & 1ULL) outb[pk[i0 + lane].y] = label;
          if ((b1 >> lane) & 1ULL) outb[pk[i0 + 64 + lane].y] = label;
          if ((b2 >> lane) & 1ULL) outb[pk[i0 + 128 + lane].y] = label;
          if ((b3 >> lane) & 1ULL) outb[pk[i0 + 192 + lane].y] = label;
        } else if (c2 < CKBCAP) {       // cached-ballot replay
          ulonglong2 ba = s_ckbA[c2];
          ulonglong2 bb = s_ckbB[c2];
          if ((ba.x >> lane) & 1ULL) outb[pk[i0 + lane].y] = label;
          if ((ba.y >> lane) & 1ULL) outb[pk[i0 + 64 + lane].y] = label;
          if ((bb.x >> lane) & 1ULL) outb[pk[i0 + 128 + lane].y] = label;
          if ((bb.y >> lane) & 1ULL) outb[pk[i0 + 192 + lane].y] = label;
        } else {                        // overflow chunks: recompute
          #pragma unroll
          for (int g = 0; g < 4; ++g) {
            int idx = (g << 6) + lane;
            if (idx >= ss && idx < en &&
                ((idx >= lo && idx < h2) ||
                 prop_test(emb[i0 + idx], cx, cy, den0, den1, inv0, inv1)))
              outb[pk[i0 + idx].y] = label;
          }
        }
      }
    }

    // ---- rescans: only segments whose cached winner was removed ----
    if (ndRaw > DLCAP) {
      for (int s = wid; s < NSEG; s += 16)
        seg_rescan(s, V, lane, s_uncl, pk, emb, base, s_segkey, s_segci,
                   s_segaux, s_segaux2, true);
    } else {
      for (int d = wid; d < ndRaw; d += 16)
        seg_rescan(s_dlist[d], V, lane, s_uncl, pk, emb, base, s_segkey,
                   s_segci, s_segaux, s_segaux2, true);
    }
    __syncthreads();   // B2
    t++;
  }
}

// ---------------- launch ----------------

extern "C" void kernel_launch(void* const* d_in, const int* in_sizes, int n_in,
                              void* d_out, int out_size, void* d_ws, size_t ws_size,
                              hipStream_t stream) {
  const float* in = (const float*)d_in[0];
  int* out = (int*)d_out;

  size_t hist_bytes = (size_t)BATCH * NCELL * sizeof(int);
  size_t off_bytes  = (size_t)BATCH * (NCELL + 1) * sizeof(int);
  size_t cur_bytes  = (size_t)BATCH * NCELL * sizeof(int);
  size_t emb_bytes  = (size_t)BATCH * CCAP * sizeof(float2);
  size_t pk_bytes   = (size_t)BATCH * CCAP * sizeof(int2);

  size_t o_hist = 256;
  size_t o_off  = (o_hist + hist_bytes + 255) & ~(size_t)255;
  size_t o_cur  = (o_off + off_bytes + 255) & ~(size_t)255;
  size_t o_emb  = (o_cur + cur_bytes + 255) & ~(size_t)255;
  size_t o_pk   = (o_emb + emb_bytes + 255) & ~(size_t)255;
  size_t need   = o_pk + pk_bytes;

  if (ws_size < need) {
    fill_kernel<<<(out_size + 1023) / 1024, 1024, 0, stream>>>(out, 2000000, out_size);
    return;
  }

  int*    hist = (int*)((char*)d_ws + o_hist);
  int*    off  = (int*)((char*)d_ws + o_off);
  int*    cur  = (int*)((char*)d_ws + o_cur);
  float2* emb  = (float2*)((char*)d_ws + o_emb);
  int2*   pk   = (int2*)((char*)d_ws + o_pk);

  hipMemsetAsync(hist, 0, hist_bytes, stream);
  hist_kernel<<<(BATCH * NPIX) / 1024, 1024, 0, stream>>>(in, out, hist);
  scan_kernel<<<BATCH, 1024, 0, stream>>>(hist, off, cur);
  scatter_kernel<<<(BATCH * NPIX) / 1024, 1024, 0, stream>>>(in, cur, emb, pk);
  cluster_kernel<<<BATCH, 1024, 0, stream>>>(in, out, emb, pk, off);
}